// Round 1
// baseline (226.097 us; speedup 1.0000x reference)
//
#include <hip/hip_runtime.h>

#define P 10
#define PM 9
// lower-triangular flat index, requires a>=b
#define TRI(a,b) ((a)*((a)+1)/2 + (b))

__device__ __forceinline__ int tri_sym(int a, int b) { return a >= b ? TRI(a, b) : TRI(b, a); }

__global__ __launch_bounds__(256, 1)
void spodnet_kernel(const float* __restrict__ Theta,
                    const float* __restrict__ noise,
                    float* __restrict__ out,
                    int B, int K)
{
    int b = blockIdx.x * blockDim.x + threadIdx.x;
    if (b >= B) return;

    // ---- load Theta[b] (100 floats, thread-contiguous, float4) ----
    float tin[P * P];
    const float4* tp = reinterpret_cast<const float4*>(Theta + (size_t)b * (P * P));
#pragma unroll
    for (int q = 0; q < (P * P) / 4; q++) {
        float4 t = tp[q];
        tin[4 * q + 0] = t.x; tin[4 * q + 1] = t.y;
        tin[4 * q + 2] = t.z; tin[4 * q + 3] = t.w;
    }
    // symmetric: keep lower triangle only (upper regs die -> DCE)
    float Tl[55];
#pragma unroll
    for (int i = 0; i < P; i++)
#pragma unroll
        for (int j = 0; j <= i; j++)
            Tl[TRI(i, j)] = tin[i * P + j];

    // ---- Cholesky in place: Tl becomes L (lower) ----
#pragma unroll
    for (int j = 0; j < P; j++) {
        float s = Tl[TRI(j, j)];
#pragma unroll
        for (int k = 0; k < j; k++) s -= Tl[TRI(j, k)] * Tl[TRI(j, k)];
        float ljj = sqrtf(s);
        float ilj = 1.0f / ljj;
        Tl[TRI(j, j)] = ljj;
#pragma unroll
        for (int i = j + 1; i < P; i++) {
            float s2 = Tl[TRI(i, j)];
#pragma unroll
            for (int k = 0; k < j; k++) s2 -= Tl[TRI(i, k)] * Tl[TRI(j, k)];
            Tl[TRI(i, j)] = s2 * ilj;
        }
    }

    // ---- Linv = L^-1 (lower) ----
    float Li[55];
#pragma unroll
    for (int j = 0; j < P; j++) {
        float idj = 1.0f / Tl[TRI(j, j)];
        Li[TRI(j, j)] = idj;
#pragma unroll
        for (int i = j + 1; i < P; i++) {
            float s = 0.f;
#pragma unroll
            for (int k = j; k < i; k++) s += Tl[TRI(i, k)] * Li[TRI(k, j)];
            Li[TRI(i, j)] = -s / Tl[TRI(i, i)];
        }
    }

    // ---- W = Linv^T * Linv (lower triangle) ----
    float Wl[55];
#pragma unroll
    for (int i = 0; i < P; i++)
#pragma unroll
        for (int j = 0; j <= i; j++) {
            float s = 0.f;
#pragma unroll
            for (int k = i; k < P; k++) s += Li[TRI(k, i)] * Li[TRI(k, j)];
            Wl[TRI(i, j)] = s;
        }

    // ---- K passes of 10 column updates ----
    float diag[P];
    const float gy = 1.0f;
    for (int k = 0; k < K; k++) {
#pragma unroll
        for (int col = 0; col < P; col++) {
            float v_[PM], w12[PM], y_[PM];
#pragma unroll
            for (int t = 0; t < PM; t++) v_[t] = noise[k * P * PM + col * PM + t]; // uniform -> SGPR
            float w22 = Wl[TRI(col, col)];
#pragma unroll
            for (int t = 0; t < PM; t++) {
                int it = t < col ? t : t + 1;
                w12[t] = Wl[tri_sym(it, col)];
            }
            // y = W11 * v
#pragma unroll
            for (int t = 0; t < PM; t++) {
                int it = t < col ? t : t + 1;
                float s = 0.f;
#pragma unroll
                for (int u = 0; u < PM; u++) {
                    int iu = u < col ? u : u + 1;
                    s += Wl[tri_sym(it, iu)] * v_[u];
                }
                y_[t] = s;
            }
            float d = 0.f, schur = 0.f;
#pragma unroll
            for (int t = 0; t < PM; t++) { d += w12[t] * v_[t]; schur += v_[t] * y_[t]; }
            float t22n = gy + schur;
            diag[col] = t22n;
            // u = inv_T11 * v = y - (d/w22) * w12 ; s1 = v^T inv_T11 v
            float dw = d / w22;
            float u_[PM]; float s1 = 0.f;
#pragma unroll
            for (int t = 0; t < PM; t++) { u_[t] = y_[t] - dw * w12[t]; s1 += v_[t] * u_[t]; }
            float w22n = 1.0f / (t22n - s1);
            float w12n[PM];
#pragma unroll
            for (int t = 0; t < PM; t++) w12n[t] = -w22n * u_[t];
            // W11 <- W11 - (1/w22) w12 w12^T + w22n * w12n w12n^T   (lower triangle)
            float a = -1.0f / w22;
#pragma unroll
            for (int t = 0; t < PM; t++) {
                int it = t < col ? t : t + 1;
#pragma unroll
                for (int u2 = 0; u2 <= t; u2++) {
                    int iu = u2 < col ? u2 : u2 + 1;
                    Wl[TRI(it, iu)] += a * w12[t] * w12[u2] + w22n * w12n[t] * w12n[u2];
                }
            }
#pragma unroll
            for (int t = 0; t < PM; t++) {
                int it = t < col ? t : t + 1;
                Wl[tri_sym(it, col)] = w12n[t];
            }
            Wl[TRI(col, col)] = w22n;
        }
    }

    // ---- write output: off-diag = noise[K-1][max][min] (uniform), diag = t22n ----
    const float* nl = noise + (size_t)(K - 1) * P * PM;
    float4* op = reinterpret_cast<float4*>(out + (size_t)b * (P * P));
#pragma unroll
    for (int q = 0; q < (P * P) / 4; q++) {
        float ov[4];
#pragma unroll
        for (int c = 0; c < 4; c++) {
            int e = 4 * q + c; int i = e / P, j = e % P;
            ov[c] = (i == j) ? diag[i] : nl[(i > j ? i : j) * PM + (i < j ? i : j)];
        }
        float4 o; o.x = ov[0]; o.y = ov[1]; o.z = ov[2]; o.w = ov[3];
        op[q] = o;
    }
}

extern "C" void kernel_launch(void* const* d_in, const int* in_sizes, int n_in,
                              void* d_out, int out_size, void* d_ws, size_t ws_size,
                              hipStream_t stream) {
    const float* Theta = (const float*)d_in[0];
    const float* noise = (const float*)d_in[1];
    float* out = (float*)d_out;
    int B = in_sizes[0] / (P * P);
    int K = in_sizes[1] / (P * PM);
    int threads = 256;
    int blocks = (B + threads - 1) / threads;
    hipLaunchKernelGGL(spodnet_kernel, dim3(blocks), dim3(threads), 0, stream,
                       Theta, noise, out, B, K);
}